// Round 7
// baseline (303.669 us; speedup 1.0000x reference)
//
#include <hip/hip_runtime.h>
#include <hip/hip_bf16.h>
#include <cstdint>

using bf16 = __hip_bfloat16;
typedef __attribute__((ext_vector_type(8))) __bf16 bf16x8;
typedef __attribute__((ext_vector_type(4))) float f32x4;

#define MFMA16(a, b, c) __builtin_amdgcn_mfma_f32_16x16x32_bf16((a), (b), (c), 0, 0, 0)

#if __has_builtin(__builtin_amdgcn_exp2f)
__device__ __forceinline__ float fexp2(float x) { return __builtin_amdgcn_exp2f(x); }
#else
__device__ __forceinline__ float fexp2(float x) { return exp2f(x); }
#endif

template <int N>
__device__ __forceinline__ void vmwait() {
  asm volatile("s_waitcnt vmcnt(%0)" ::"i"(N) : "memory");
}

// Async global->LDS 16B copy. LDS dest must be wave-uniform base + lane*16.
__device__ __forceinline__ void async16(void* lds_ptr, const void* gptr) {
  auto g = reinterpret_cast<__attribute__((address_space(1))) unsigned int*>(
      reinterpret_cast<uintptr_t>(gptr));
  auto l = reinterpret_cast<__attribute__((address_space(3))) unsigned int*>(
      static_cast<unsigned int>(reinterpret_cast<uintptr_t>(lds_ptr)));
  __builtin_amdgcn_global_load_lds(g, l, 16, 0, 0);
}

// ---------------------------------------------------------------- RMSNorm ----
__global__ __launch_bounds__(256) void rmsnorm_cast_k(
    const float* __restrict__ x, const float* __restrict__ sc, bf16* __restrict__ xn) {
  const int row = blockIdx.x, tid = threadIdx.x;
  const float4* xr = (const float4*)(x + (size_t)row * 2048);
  float4 a = xr[tid * 2], b = xr[tid * 2 + 1];
  float ss = a.x * a.x + a.y * a.y + a.z * a.z + a.w * a.w +
             b.x * b.x + b.y * b.y + b.z * b.z + b.w * b.w;
#pragma unroll
  for (int d = 1; d < 64; d <<= 1) ss += __shfl_xor(ss, d);
  __shared__ float sm[4];
  if ((tid & 63) == 0) sm[tid >> 6] = ss;
  __syncthreads();
  const float rinv = rsqrtf((sm[0] + sm[1] + sm[2] + sm[3]) * (1.0f / 2048.0f) + 1e-6f);
  const float4* sp = (const float4*)sc;
  float4 s0 = sp[tid * 2], s1 = sp[tid * 2 + 1];
  union { bf16 h[8]; bf16x8 v; } o;
  o.h[0] = __float2bfloat16(a.x * rinv * s0.x);
  o.h[1] = __float2bfloat16(a.y * rinv * s0.y);
  o.h[2] = __float2bfloat16(a.z * rinv * s0.z);
  o.h[3] = __float2bfloat16(a.w * rinv * s0.w);
  o.h[4] = __float2bfloat16(b.x * rinv * s1.x);
  o.h[5] = __float2bfloat16(b.y * rinv * s1.y);
  o.h[6] = __float2bfloat16(b.z * rinv * s1.z);
  o.h[7] = __float2bfloat16(b.w * rinv * s1.w);
  *(bf16x8*)(xn + (size_t)row * 2048 + tid * 8) = o.v;
}

// ------------------------------------------------- weight transpose + cast ----
__global__ void transpose_cast_k(const float* __restrict__ W, bf16* __restrict__ Wt,
                                 int N, int ldt, int row_off, int k_off) {
  __shared__ float t[32][33];
  const int n0 = blockIdx.x * 32, k0 = blockIdx.y * 32;
  const int tx = threadIdx.x, ty = threadIdx.y;
#pragma unroll
  for (int i = 0; i < 4; ++i)
    t[ty + 8 * i][tx] = W[(size_t)(k0 + ty + 8 * i) * N + n0 + tx];
  __syncthreads();
#pragma unroll
  for (int i = 0; i < 4; ++i)
    Wt[(size_t)(row_off + n0 + ty + 8 * i) * ldt + k_off + k0 + tx] =
        __float2bfloat16(t[tx][ty + 8 * i]);
}

// V slice of QKV [4096][3072] (cols 2560..3071) -> Vt bf16 [16][128][1024]
__global__ void transpose_v_k(const bf16* __restrict__ qkv, bf16* __restrict__ vtb) {
  __shared__ bf16 t[32][33];
  const int bh = blockIdx.z, b = bh >> 2, g = bh & 3;
  const int s0 = blockIdx.x * 32, d0 = blockIdx.y * 32;
  const int tx = threadIdx.x, ty = threadIdx.y;
#pragma unroll
  for (int i = 0; i < 4; ++i)
    t[ty + 8 * i][tx] =
        qkv[(size_t)(b * 1024 + s0 + ty + 8 * i) * 3072 + 2560 + g * 128 + d0 + tx];
  __syncthreads();
#pragma unroll
  for (int i = 0; i < 4; ++i)
    vtb[((size_t)bh * 128 + d0 + ty + 8 * i) * 1024 + s0 + tx] = t[tx][ty + 8 * i];
}

// bcat layout: [0..3071]=bq|bk|bv, [3072..5119]=b1, [5120..7167]=bo+b2
__global__ void concat_bias_k(const float* __restrict__ bq, const float* __restrict__ bk,
                              const float* __restrict__ bv, const float* __restrict__ b1,
                              const float* __restrict__ bo, const float* __restrict__ b2,
                              float* __restrict__ o) {
  const int i = blockIdx.x * 256 + threadIdx.x;
  if (i < 2048) o[i] = bq[i];
  else if (i < 2560) o[i] = bk[i - 2048];
  else if (i < 3072) o[i] = bv[i - 2560];
  else if (i < 5120) o[i] = b1[i - 3072];
  else o[i] = bo[i - 5120] + b2[i - 5120];
}

// ------------------ 8/10-wave ring GEMM, per-wave 128x64 (m201 geometry) -----
// C[M][N] = A[M][K] @ Bt[N][K]^T. BM=256, BN=WN*64, WM=2 x WN waves, MI=8 NJ=4
// -> acc=128 regs, launch_bounds(.,2) pins <=256 total => 2+ waves/SIMD so the
// per-phase lgkm0 overlaps across waves (the r6 one-wave/SIMD failure mode).
// K in 32-wide slots, LDS ring of 4 slots/matrix. Per slot 2 phases:
//  P1: ds_read A-lo + B ; stageA(h+3) ; bar ; lgkm0 ; 16 MFMA ; bar
//  P2: ds_read A-hi     ; stageB(h+3) ; counted-vmcnt ; bar ; lgkm0 ; 16 MFMA ; bar
// vmcnt ledger (per wave class, FIFO): 3 slots in flight, leave 2 slots.
// EPI 0: merged QKV+W1 (col<3072 -> bf16 qkvb; else silu^2 -> bf16 gbuf).
// EPI 1: K-split partial (z = K-half): bf16 store of raw acc (bias in reduce).
#define BARRIER() \
  { asm volatile("" ::: "memory"); __builtin_amdgcn_s_barrier(); asm volatile("" ::: "memory"); }
#define LGKM0() \
  { asm volatile("s_waitcnt lgkmcnt(0)" ::: "memory"); __builtin_amdgcn_sched_barrier(0); }
#define VMW_PAIR(NH, NL)                                                     \
  { if constexpr (REMA) {                                                    \
      if (w < REMA / 64) vmwait<NH>(); else vmwait<NL>();                    \
    } else { vmwait<NL>(); }                                                 \
    __builtin_amdgcn_sched_barrier(0); }

#define RD_A(MILO)                                                                 \
  { unsigned char* ab_ = lds + sl_ * SLOTA;                                        \
    _Pragma("unroll") for (int i_ = 0; i_ < 4; ++i_) {                             \
      const int R_ = wr * 128 + ((MILO) + i_) * 16 + lo;                           \
      af[i_] = *(const bf16x8*)(ab_ + R_ * 64 + ((hi ^ ((R_ >> 1) & 3)) << 4)); } }

#define RD_B()                                                                     \
  { unsigned char* bb_ = lds + 4 * SLOTA + sl_ * SLOTB;                            \
    _Pragma("unroll") for (int j_ = 0; j_ < 4; ++j_) {                             \
      const int S_ = wc * 64 + j_ * 16 + lo;                                       \
      bf[j_] = *(const bf16x8*)(bb_ + S_ * 64 + ((hi ^ ((S_ >> 1) & 3)) << 4)); } }

#define MM(MILO)                                                                   \
  __builtin_amdgcn_s_setprio(1);                                                   \
  _Pragma("unroll") for (int i_ = 0; i_ < 4; ++i_)                                 \
    _Pragma("unroll") for (int j_ = 0; j_ < 4; ++j_)                               \
      acc[(MILO) + i_][j_] = MFMA16(af[i_], bf[j_], acc[(MILO) + i_][j_]);         \
  __builtin_amdgcn_s_setprio(0);

#define DO_SLOT(H, DOSTG, VMSTMT)                                                  \
  { const int h_ = (H); const int sl_ = h_ & 3;                                    \
    RD_A(0); RD_B();                                                               \
    if (DOSTG) stgA(h_ + 3);                                                       \
    BARRIER(); LGKM0();                                                            \
    MM(0);                                                                         \
    BARRIER();                                                                     \
    RD_A(4);                                                                       \
    if (DOSTG) stgB(h_ + 3);                                                       \
    VMSTMT;                                                                        \
    BARRIER(); LGKM0();                                                            \
    MM(4);                                                                         \
    BARRIER(); }

template <int WN, int EPI>
__global__ __launch_bounds__(WN * 128, 2) void gemm8(
    const bf16* __restrict__ A, const bf16* __restrict__ A2,
    const bf16* __restrict__ Bt, const float* __restrict__ bias,
    void* __restrict__ out0, void* __restrict__ out1, int ldB) {
  constexpr int T = WN * 128;
  constexpr int BM = 256;
  constexpr int BN = WN * 64;
  constexpr int SLOTA = BM * 64;
  constexpr int SLOTB = BN * 64;
  constexpr int SWEEP = T * 16;
  constexpr int FULLA = SLOTA / SWEEP, REMA = (SLOTA % SWEEP) / 16;
  constexpr int FULLB = SLOTB / SWEEP, REMB = (SLOTB % SWEEP) / 16;
  static_assert(REMB == 0 && (REMA % 64) == 0, "sweep alignment");
  constexpr int LL = FULLA + FULLB, LH = LL + (REMA ? 1 : 0);
  extern __shared__ unsigned char lds[];

  const int tid = threadIdx.x, lane = tid & 63, w = tid >> 6;
  const int wr = w / WN, wc = w % WN;
  const int hi = lane >> 4, lo = lane & 15;

  // bijective XCD swizzle over 256 blocks
  const int lid = (blockIdx.z * gridDim.y + blockIdx.y) * gridDim.x + blockIdx.x;
  const int swz = (lid & 7) * 32 + (lid >> 3);
  const int brow = (swz & 15) * BM;
  int bcol, z;
  if constexpr (EPI == 1) {
    const int r = swz >> 4;
    bcol = (r & 7) * BN;
    z = r >> 3;
  } else {
    bcol = (swz >> 4) * BN;
    z = 0;
  }
  const bf16* Ab = (EPI == 1 && z) ? A2 : A;
  const int koff = (EPI == 1) ? z * 2048 : 0;

  const int NS = 64;  // K=2048 per block, 32-wide slots

  // staging source precompute (element offsets; inverse-swizzled columns)
  const bf16* Asrc[FULLA + (REMA ? 1 : 0)];
#pragma unroll
  for (int i = 0; i < FULLA + (REMA ? 1 : 0); ++i) {
    const int o = i * SWEEP + tid * 16;
    const int r = o >> 6, c = ((o >> 4) & 3) ^ ((r >> 1) & 3);
    Asrc[i] = Ab + (size_t)(brow + r) * 2048 + c * 8;
  }
  const bf16* Bsrc[FULLB];
#pragma unroll
  for (int i = 0; i < FULLB; ++i) {
    const int o = i * SWEEP + tid * 16;
    const int r = o >> 6, c = ((o >> 4) & 3) ^ ((r >> 1) & 3);
    Bsrc[i] = Bt + (size_t)(bcol + r) * ldB + koff + c * 8;
  }

  auto stgA = [&](int h) {
    unsigned char* ab = lds + (h & 3) * SLOTA;
    const int kb = h * 32;
#pragma unroll
    for (int i = 0; i < FULLA; ++i)
      async16(ab + i * SWEEP + tid * 16, Asrc[i] + kb);
    if constexpr (REMA != 0) {
      if (tid < REMA)
        async16(ab + FULLA * SWEEP + tid * 16, Asrc[FULLA] + kb);
    }
  };
  auto stgB = [&](int h) {
    unsigned char* bb = lds + 4 * SLOTA + (h & 3) * SLOTB;
    const int kb = h * 32;
#pragma unroll
    for (int i = 0; i < FULLB; ++i)
      async16(bb + i * SWEEP + tid * 16, Bsrc[i] + kb);
  };

  stgA(0); stgB(0); stgA(1); stgB(1); stgA(2); stgB(2);
  VMW_PAIR(2 * LH, 2 * LL);
  BARRIER();

  f32x4 acc[8][4] = {};
  bf16x8 af[4], bf[4];

  for (int h = 0; h < NS - 3; ++h) { DO_SLOT(h, true, VMW_PAIR(2 * LH, 2 * LL)); }
  DO_SLOT(NS - 3, false, VMW_PAIR(LH, LL));
  DO_SLOT(NS - 2, false, VMW_PAIR(0, 0));
  DO_SLOT(NS - 1, false, (void)0);

#pragma unroll
  for (int mi = 0; mi < 8; ++mi) {
    const int row0 = brow + wr * 128 + mi * 16 + hi * 4;
#pragma unroll
    for (int nj = 0; nj < 4; ++nj) {
      const int col = bcol + wc * 64 + nj * 16 + lo;
#pragma unroll
      for (int r = 0; r < 4; ++r) {
        const int row = row0 + r;
        if constexpr (EPI == 0) {
          float v = acc[mi][nj][r] + bias[col];
          if (col < 3072) {
            ((bf16*)out0)[(size_t)row * 3072 + col] = __float2bfloat16(v);
          } else {
            const float sg = 1.0f / (1.0f + __expf(-v));
            ((bf16*)out1)[(size_t)row * 2048 + (col - 3072)] =
                __float2bfloat16(v * sg * v);
          }
        } else {
          bf16* P = (bf16*)(z ? out1 : out0);
          P[(size_t)row * 2048 + col] = __float2bfloat16(acc[mi][nj][r]);
        }
      }
    }
  }
}

// out = x + P0 + P1 + bias  (f32 out, bf16 partials)
__global__ __launch_bounds__(256) void reduce_k(
    const float* __restrict__ x, const bf16* __restrict__ P0,
    const bf16* __restrict__ P1, const float* __restrict__ bias,
    float* __restrict__ out) {
  const int n4 = 4096 * 2048 / 4;
  for (int i = blockIdx.x * 256 + threadIdx.x; i < n4; i += gridDim.x * 256) {
    float4 xv = ((const float4*)x)[i];
    ushort4 a = ((const ushort4*)P0)[i];
    ushort4 b = ((const ushort4*)P1)[i];
    float4 bv = ((const float4*)bias)[i & 511];
    float4 o;
    o.x = xv.x + __uint_as_float((unsigned)a.x << 16) + __uint_as_float((unsigned)b.x << 16) + bv.x;
    o.y = xv.y + __uint_as_float((unsigned)a.y << 16) + __uint_as_float((unsigned)b.y << 16) + bv.y;
    o.z = xv.z + __uint_as_float((unsigned)a.z << 16) + __uint_as_float((unsigned)b.z << 16) + bv.z;
    o.w = xv.w + __uint_as_float((unsigned)a.w << 16) + __uint_as_float((unsigned)b.w << 16) + bv.w;
    ((float4*)out)[i] = o;
  }
}

// --------------------------------------------------------------- attention ----
__global__ __launch_bounds__(256, 4) void attn_fwd(
    const bf16* __restrict__ qkv, const bf16* __restrict__ vtb, bf16* __restrict__ out) {
  __shared__ __align__(16) unsigned char alds[40960];
  unsigned char* Ks = alds;
  unsigned char* Vs = alds + 16384;
  unsigned char* Ps = alds + 32768;
  const int tid = threadIdx.x, lane = tid & 63, w = tid >> 6;
  const int hi = lane >> 4, lo = lane & 15;
  const int qt = blockIdx.x, bh = blockIdx.y;
  const int b = bh >> 4, h = bh & 15, g = h >> 2;
  const size_t tok0 = (size_t)b * 1024;
  const int q0 = qt * 64;

  bf16x8 qf[4];
  {
    const bf16* qp = qkv + (tok0 + q0 + w * 16 + lo) * 3072 + h * 128 + hi * 8;
#pragma unroll
    for (int kc = 0; kc < 4; ++kc) qf[kc] = *(const bf16x8*)(qp + kc * 32);
  }

  float m2 = -1e30f, lsum = 0.f;
  f32x4 oacc[8] = {};
  const float c2 = 0.08838834764831845f * 1.44269504088896f;

  const int o = tid * 16;
  const bf16* kbase = qkv + tok0 * 3072 + 2048 + g * 128;
  const bf16* vbase = vtb + (size_t)(b * 4 + g) * 128 * 1024;
  unsigned char* Pw = Ps + w * 2048;

  for (int t = 0; t < 16; ++t) {
    const int kb = t * 64;
#pragma unroll
    for (int rd = 0; rd < 4; ++rd) {
      const int oo = o + rd * 4096;
      const int rK = oo >> 8, cK = ((oo >> 4) & 15) ^ (rK & 15);
      const int rV = oo >> 7, cV = ((oo >> 4) & 7) ^ (rV & 7);
      async16(Ks + oo, kbase + (size_t)(kb + rK) * 3072 + cK * 8);
      async16(Vs + oo, vbase + (size_t)rV * 1024 + kb + cV * 8);
    }
    __syncthreads();

    f32x4 sc[4] = {};
#pragma unroll
    for (int kc = 0; kc < 4; ++kc) {
#pragma unroll
      for (int kg = 0; kg < 4; ++kg) {
        const int row = kg * 16 + lo;
        bf16x8 kf = *(const bf16x8*)(Ks + row * 256 + ((((kc << 2) + hi) ^ (row & 15)) << 4));
        sc[kg] = MFMA16(kf, qf[kc], sc[kg]);
      }
    }

    float mx = sc[0][0];
#pragma unroll
    for (int kg = 0; kg < 4; ++kg)
#pragma unroll
      for (int r = 0; r < 4; ++r) mx = fmaxf(mx, sc[kg][r]);
    mx = fmaxf(mx, __shfl_xor(mx, 16));
    mx = fmaxf(mx, __shfl_xor(mx, 32));
    mx *= c2;
    const float mn = fmaxf(m2, mx);
    const float corr = fexp2(m2 - mn);
    m2 = mn;

    float rs = 0.f;
#pragma unroll
    for (int kg = 0; kg < 4; ++kg) {
      union { bf16 hh[4]; uint2 v; } pk;
#pragma unroll
      for (int r = 0; r < 4; ++r) {
        const float p = fexp2(sc[kg][r] * c2 - mn);
        rs += p;
        pk.hh[r] = __float2bfloat16(p);
      }
      *(uint2*)(Pw + lo * 128 + ((((kg << 1) + (hi >> 1)) ^ (lo & 7)) << 4) +
                ((hi & 1) << 3)) = pk.v;
    }
    rs += __shfl_xor(rs, 16);
    rs += __shfl_xor(rs, 32);
    lsum = lsum * corr + rs;

    float corr_r[4];
#pragma unroll
    for (int r = 0; r < 4; ++r) corr_r[r] = __shfl(corr, hi * 4 + r);
#pragma unroll
    for (int dg = 0; dg < 8; ++dg)
#pragma unroll
      for (int r = 0; r < 4; ++r) oacc[dg][r] *= corr_r[r];

    asm volatile("s_waitcnt lgkmcnt(0)" ::: "memory");

    bf16x8 pf[2];
#pragma unroll
    for (int kc = 0; kc < 2; ++kc)
      pf[kc] = *(const bf16x8*)(Pw + lo * 128 + ((((kc << 2) + hi) ^ (lo & 7)) << 4));
#pragma unroll
    for (int dg = 0; dg < 8; ++dg) {
#pragma unroll
      for (int kc = 0; kc < 2; ++kc) {
        const int vrow = dg * 16 + lo;
        bf16x8 vf = *(const bf16x8*)(Vs + vrow * 128 + ((((kc << 2) + hi) ^ (vrow & 7)) << 4));
        oacc[dg] = MFMA16(pf[kc], vf, oacc[dg]);
      }
    }
    __syncthreads();
  }

  const float linv = 1.0f / lsum;
  float lr[4];
#pragma unroll
  for (int r = 0; r < 4; ++r) lr[r] = __shfl(linv, hi * 4 + r);
  bf16* op = out + (tok0 + q0 + w * 16 + hi * 4) * 2048 + h * 128 + lo;
#pragma unroll
  for (int dg = 0; dg < 8; ++dg)
#pragma unroll
    for (int r = 0; r < 4; ++r)
      op[(size_t)r * 2048 + dg * 16] = __float2bfloat16(oacc[dg][r] * lr[r]);
}

// ------------------------------------------------------------------ launch ----
extern "C" void kernel_launch(void* const* d_in, const int* in_sizes, int n_in,
                              void* d_out, int out_size, void* d_ws, size_t ws_size,
                              hipStream_t stream) {
  (void)in_sizes; (void)n_in; (void)out_size; (void)ws_size;
  const float* x  = (const float*)d_in[0];
  const float* s1 = (const float*)d_in[1];
  const float* Wq = (const float*)d_in[2];
  const float* bq = (const float*)d_in[3];
  const float* Wk = (const float*)d_in[4];
  const float* bk = (const float*)d_in[5];
  const float* Wv = (const float*)d_in[6];
  const float* bv = (const float*)d_in[7];
  const float* Wo = (const float*)d_in[8];
  const float* bo = (const float*)d_in[9];
  const float* W1 = (const float*)d_in[10];
  const float* b1 = (const float*)d_in[11];
  const float* W2 = (const float*)d_in[12];
  const float* b2 = (const float*)d_in[13];
  float* outp = (float*)d_out;

  char* ws = (char*)d_ws;
  bf16*  xn     = (bf16*)(ws + 0);           // 16.78 MB; dead after gemm8<0>
  bf16*  vtb    = (bf16*)(ws + 0);           // 4.19 MB, aliases dead xn; dead after attn
  bf16*  P0     = (bf16*)(ws + 0);           // 16.78 MB partial, aliases dead vtb/xn
  bf16*  wcatT  = (bf16*)(ws + 16777216);    // [5120][2048] 20.97 MB; dead after gemm8<0>
  bf16*  attnb  = (bf16*)(ws + 16777216);    // [4096][2048] 16.78 MB, aliases dead wcatT
  float* bcat   = (float*)(ws + 37748736);   // 28 KB
  bf16*  wcat2T = (bf16*)(ws + 37781504);    // [2048][4096] 16.78 MB (Wo|W2 K-concat)
  bf16*  qkvb   = (bf16*)(ws + 54558720);    // [4096][3072] 25.17 MB; dead after attn
  bf16*  P1     = (bf16*)(ws + 54558720);    // 16.78 MB partial, aliases dead qkvb
  bf16*  gbuf   = (bf16*)(ws + 79724544);    // [4096][2048] 16.78 MB

  const dim3 b32x8(32, 8);
  rmsnorm_cast_k<<<dim3(4096), dim3(256), 0, stream>>>(x, s1, xn);
  concat_bias_k<<<dim3(28), dim3(256), 0, stream>>>(bq, bk, bv, b1, bo, b2, bcat);
  transpose_cast_k<<<dim3(64, 64), b32x8, 0, stream>>>(Wq, wcatT, 2048, 2048, 0, 0);
  transpose_cast_k<<<dim3(16, 64), b32x8, 0, stream>>>(Wk, wcatT, 512, 2048, 2048, 0);
  transpose_cast_k<<<dim3(16, 64), b32x8, 0, stream>>>(Wv, wcatT, 512, 2048, 2560, 0);
  transpose_cast_k<<<dim3(64, 64), b32x8, 0, stream>>>(W1, wcatT, 2048, 2048, 3072, 0);
  transpose_cast_k<<<dim3(64, 64), b32x8, 0, stream>>>(Wo, wcat2T, 2048, 4096, 0, 0);
  transpose_cast_k<<<dim3(64, 64), b32x8, 0, stream>>>(W2, wcat2T, 2048, 4096, 0, 2048);
  // merged QKV + W1: [4096,2048] x [2048,5120], 256x320 tiles, 10 waves
  gemm8<5, 0><<<dim3(16, 16), dim3(640), 147456, stream>>>(
      xn, (const bf16*)nullptr, wcatT, bcat, (void*)qkvb, (void*)gbuf, 2048);
  transpose_v_k<<<dim3(32, 4, 16), b32x8, 0, stream>>>(qkvb, vtb);
  attn_fwd<<<dim3(16, 64), dim3(256), 0, stream>>>(qkvb, vtb, attnb);
  // Pz = (z ? gbuf@W2-half : attnb@Wo-half), 256x256 tiles, K-split 2
  gemm8<4, 1><<<dim3(16, 8, 2), dim3(512), 131072, stream>>>(
      attnb, gbuf, wcat2T, (const float*)nullptr, (void*)P0, (void*)P1, 4096);
  // out = x + P0 + P1 + (bo+b2)
  reduce_k<<<dim3(2048), dim3(256), 0, stream>>>(x, P0, P1, bcat + 5120, outp);
}

// Round 8
// 254.238 us; speedup vs baseline: 1.1944x; 1.1944x over previous
//
#include <hip/hip_runtime.h>
#include <hip/hip_bf16.h>
#include <cstdint>

using bf16 = __hip_bfloat16;
typedef __attribute__((ext_vector_type(8))) __bf16 bf16x8;
typedef __attribute__((ext_vector_type(4))) float f32x4;

#define MFMA16(a, b, c) __builtin_amdgcn_mfma_f32_16x16x32_bf16((a), (b), (c), 0, 0, 0)

#if __has_builtin(__builtin_amdgcn_exp2f)
__device__ __forceinline__ float fexp2(float x) { return __builtin_amdgcn_exp2f(x); }
#else
__device__ __forceinline__ float fexp2(float x) { return exp2f(x); }
#endif

// Async global->LDS 16B copy. LDS dest must be wave-uniform base + lane*16.
__device__ __forceinline__ void async16(void* lds_ptr, const void* gptr) {
  auto g = reinterpret_cast<__attribute__((address_space(1))) unsigned int*>(
      reinterpret_cast<uintptr_t>(gptr));
  auto l = reinterpret_cast<__attribute__((address_space(3))) unsigned int*>(
      static_cast<unsigned int>(reinterpret_cast<uintptr_t>(lds_ptr)));
  __builtin_amdgcn_global_load_lds(g, l, 16, 0, 0);
}

// ---------------------------------------------------------------- RMSNorm ----
__global__ __launch_bounds__(256) void rmsnorm_cast_k(
    const float* __restrict__ x, const float* __restrict__ sc, bf16* __restrict__ xn) {
  const int row = blockIdx.x, tid = threadIdx.x;
  const float4* xr = (const float4*)(x + (size_t)row * 2048);
  float4 a = xr[tid * 2], b = xr[tid * 2 + 1];
  float ss = a.x * a.x + a.y * a.y + a.z * a.z + a.w * a.w +
             b.x * b.x + b.y * b.y + b.z * b.z + b.w * b.w;
#pragma unroll
  for (int d = 1; d < 64; d <<= 1) ss += __shfl_xor(ss, d);
  __shared__ float sm[4];
  if ((tid & 63) == 0) sm[tid >> 6] = ss;
  __syncthreads();
  const float rinv = rsqrtf((sm[0] + sm[1] + sm[2] + sm[3]) * (1.0f / 2048.0f) + 1e-6f);
  const float4* sp = (const float4*)sc;
  float4 s0 = sp[tid * 2], s1 = sp[tid * 2 + 1];
  union { bf16 h[8]; bf16x8 v; } o;
  o.h[0] = __float2bfloat16(a.x * rinv * s0.x);
  o.h[1] = __float2bfloat16(a.y * rinv * s0.y);
  o.h[2] = __float2bfloat16(a.z * rinv * s0.z);
  o.h[3] = __float2bfloat16(a.w * rinv * s0.w);
  o.h[4] = __float2bfloat16(b.x * rinv * s1.x);
  o.h[5] = __float2bfloat16(b.y * rinv * s1.y);
  o.h[6] = __float2bfloat16(b.z * rinv * s1.z);
  o.h[7] = __float2bfloat16(b.w * rinv * s1.w);
  *(bf16x8*)(xn + (size_t)row * 2048 + tid * 8) = o.v;
}

// ------------------------------------------------- weight transpose + cast ----
// W f32 [2048][N] -> Wt[(row_off + n) * ldt + k_off + k] = bf16(W[k][n])
__global__ void transpose_cast_k(const float* __restrict__ W, bf16* __restrict__ Wt,
                                 int N, int ldt, int row_off, int k_off) {
  __shared__ float t[32][33];
  const int n0 = blockIdx.x * 32, k0 = blockIdx.y * 32;
  const int tx = threadIdx.x, ty = threadIdx.y;
#pragma unroll
  for (int i = 0; i < 4; ++i)
    t[ty + 8 * i][tx] = W[(size_t)(k0 + ty + 8 * i) * N + n0 + tx];
  __syncthreads();
#pragma unroll
  for (int i = 0; i < 4; ++i)
    Wt[(size_t)(row_off + n0 + ty + 8 * i) * ldt + k_off + k0 + tx] =
        __float2bfloat16(t[tx][ty + 8 * i]);
}

// V slice of QKV [4096][3072] (cols 2560..3071) -> Vt bf16 [16][128][1024]
__global__ void transpose_v_k(const bf16* __restrict__ qkv, bf16* __restrict__ vtb) {
  __shared__ bf16 t[32][33];
  const int bh = blockIdx.z, b = bh >> 2, g = bh & 3;
  const int s0 = blockIdx.x * 32, d0 = blockIdx.y * 32;
  const int tx = threadIdx.x, ty = threadIdx.y;
#pragma unroll
  for (int i = 0; i < 4; ++i)
    t[ty + 8 * i][tx] =
        qkv[(size_t)(b * 1024 + s0 + ty + 8 * i) * 3072 + 2560 + g * 128 + d0 + tx];
  __syncthreads();
#pragma unroll
  for (int i = 0; i < 4; ++i)
    vtb[((size_t)bh * 128 + d0 + ty + 8 * i) * 1024 + s0 + tx] = t[tx][ty + 8 * i];
}

// bcat layout: [0..3071]=bq|bk|bv, [3072..5119]=b1, [5120..7167]=bo+b2
__global__ void concat_bias_k(const float* __restrict__ bq, const float* __restrict__ bk,
                              const float* __restrict__ bv, const float* __restrict__ b1,
                              const float* __restrict__ bo, const float* __restrict__ b2,
                              float* __restrict__ o) {
  const int i = blockIdx.x * 256 + threadIdx.x;
  if (i < 2048) o[i] = bq[i];
  else if (i < 2560) o[i] = bk[i - 2048];
  else if (i < 3072) o[i] = bv[i - 2560];
  else if (i < 5120) o[i] = b1[i - 3072];
  else o[i] = bo[i - 5120] + b2[i - 5120];
}

// --------------------- 8-wave ring GEMM, fat per-wave panels ----------------
// C[M][N] = A[M][K] @ Bt[N][K]^T. Block = (WM*MI*16) x (WN*NJ*16), 512 thr,
// 8 waves each owning a (MI*16) x (NJ*16) panel. K processed in 32-wide slots,
// LDS ring of 4 slots per matrix. Per slot: 2 phases
//   {ds_read fragments ; stage slot h+3 ; barrier ; lgkm(0) ; setprio MFMA ; barrier}
// with one counted vmcnt (2 slots in flight, FIFO-oldest semantics) per slot.
// A is always ld 2048. EPI==1 reads A for k<2048 and A2 for k>=2048 (K=4096).
#define BARRIER() \
  { asm volatile("" ::: "memory"); __builtin_amdgcn_s_barrier(); asm volatile("" ::: "memory"); }
#define LGKM0() \
  { asm volatile("s_waitcnt lgkmcnt(0)" ::: "memory"); __builtin_amdgcn_sched_barrier(0); }
#define VM_MAIN                                                          \
  { if constexpr (LPS == 4) { asm volatile("s_waitcnt vmcnt(8)" ::: "memory"); } \
    else { asm volatile("s_waitcnt vmcnt(6)" ::: "memory"); }            \
    __builtin_amdgcn_sched_barrier(0); }
#define VM_ONE                                                           \
  { if constexpr (LPS == 4) { asm volatile("s_waitcnt vmcnt(4)" ::: "memory"); } \
    else { asm volatile("s_waitcnt vmcnt(3)" ::: "memory"); }            \
    __builtin_amdgcn_sched_barrier(0); }
#define VM_ZERO \
  { asm volatile("s_waitcnt vmcnt(0)" ::: "memory"); __builtin_amdgcn_sched_barrier(0); }

#define READ_AF(MILO)                                                              \
  { unsigned char* ab_ = lds + (h_ & 3) * SLOTA;                                   \
    _Pragma("unroll") for (int i_ = 0; i_ < MI / 2; ++i_) {                        \
      const int R_ = arow0 + ((MILO) + i_) * 16;                                   \
      af[i_] = *(const bf16x8*)(ab_ + R_ * 64 + ((hi ^ ((R_ >> 1) & 3)) << 4)); } }

#define READ_BF()                                                                  \
  { unsigned char* bb_ = lds + 4 * SLOTA + (h_ & 3) * SLOTB;                       \
    _Pragma("unroll") for (int j_ = 0; j_ < NJ; ++j_) {                            \
      const int S_ = bcol0 + j_ * 16;                                              \
      bf[j_] = *(const bf16x8*)(bb_ + S_ * 64 + ((hi ^ ((S_ >> 1) & 3)) << 4)); } }

#define MFMA_HALF(MILO)                                                            \
  __builtin_amdgcn_s_setprio(1);                                                   \
  _Pragma("unroll") for (int i_ = 0; i_ < MI / 2; ++i_)                            \
    _Pragma("unroll") for (int j_ = 0; j_ < NJ; ++j_)                              \
      acc[(MILO) + i_][j_] = MFMA16(af[i_], bf[j_], acc[(MILO) + i_][j_]);         \
  __builtin_amdgcn_s_setprio(0);

#define GSLOT(H, DOSTG, VMSTMT)                                                    \
  { const int h_ = (H);                                                            \
    READ_AF(0); READ_BF();                                                         \
    if (DOSTG) stgA(h_ + 3);                                                       \
    BARRIER(); LGKM0();                                                            \
    MFMA_HALF(0);                                                                  \
    BARRIER();                                                                     \
    READ_AF(MI / 2);                                                               \
    if (DOSTG) stgB(h_ + 3);                                                       \
    VMSTMT;                                                                        \
    BARRIER(); LGKM0();                                                            \
    MFMA_HALF(MI / 2);                                                             \
    BARRIER(); }

template <int MI, int NJ, int WM, int WN, int EPI>
__global__ __launch_bounds__(512, 1) void gemm8(
    const bf16* __restrict__ A, const bf16* __restrict__ A2,
    const bf16* __restrict__ Bt, const float* __restrict__ bias,
    const float* __restrict__ res, void* __restrict__ out0,
    void* __restrict__ out1, int K) {
  constexpr int BM = WM * MI * 16;
  constexpr int BN = WN * NJ * 16;
  constexpr int SLOTA = BM * 64;   // bytes per A 32-K slot
  constexpr int SLOTB = BN * 64;
  constexpr int NSWA = SLOTA / 8192;
  constexpr int NSWB = SLOTB / 8192;
  constexpr int FRACB = SLOTB % 8192;  // partial sweep (first FRACB/16 threads)
  constexpr int LPS = NSWA + NSWB;     // ledger loads/slot (min over waves)
  extern __shared__ unsigned char lds[];

  const int tid = threadIdx.x, lane = tid & 63, w = tid >> 6;
  const int wr = w / WN, wc = w % WN;
  const int hi = lane >> 4, lo = lane & 15;

  // Rectangular per-XCD mapping over the 16x16 grid (256 blocks):
  // XCD x = lid&7 (hw round-robin), j = lid>>3 in [0,32). XCD x owns the
  // 4-brow x 8-bcol rectangle -> per-XCD K-window working set ~460 KB << L2.
  // Bijection: brow=(x&3)*4+(j&3), bcol=(x>>2)*8+(j>>2).
  const int lid = blockIdx.y * 16 + blockIdx.x;
  const int xj = lid & 7, jj = lid >> 3;
  const int brow = ((xj & 3) * 4 + (jj & 3)) * BM;
  const int bcol = ((xj >> 2) * 8 + (jj >> 2)) * BN;

  const int NS = K >> 5;

  // staging source precompute (A ld fixed 2048; B ld = K)
  size_t offA[NSWA];
#pragma unroll
  for (int i = 0; i < NSWA; ++i) {
    const int o = i * 8192 + tid * 16;
    const int r = o >> 6;
    const int c = ((((o >> 4) & 3) ^ ((r >> 1) & 3)) << 3);
    offA[i] = (size_t)(brow + r) * 2048 + c;
  }
  const bf16* srcB[NSWB + (FRACB ? 1 : 0)];
#pragma unroll
  for (int i = 0; i < NSWB + (FRACB ? 1 : 0); ++i) {
    const int o = i * 8192 + tid * 16;
    const int r = o >> 6;
    const int c = ((((o >> 4) & 3) ^ ((r >> 1) & 3)) << 3);
    srcB[i] = Bt + (size_t)(bcol + r) * K + c;
  }

  auto stgA = [&](int h) {
    unsigned char* ab = lds + (h & 3) * SLOTA;
    const int kb = h * 32;
    const bf16* base;
    int ko;
    if constexpr (EPI == 1) { base = (kb < 2048) ? A : A2; ko = kb & 2047; }
    else { base = A; ko = kb; }
#pragma unroll
    for (int i = 0; i < NSWA; ++i)
      async16(ab + i * 8192 + tid * 16, base + offA[i] + ko);
  };
  auto stgB = [&](int h) {
    unsigned char* bb = lds + 4 * SLOTA + (h & 3) * SLOTB;
    const int kb = h * 32;
#pragma unroll
    for (int i = 0; i < NSWB; ++i)
      async16(bb + i * 8192 + tid * 16, srcB[i] + kb);
    if constexpr (FRACB != 0) {
      if (tid < FRACB / 16)
        async16(bb + NSWB * 8192 + tid * 16, srcB[NSWB] + kb);
    }
  };

  const int arow0 = wr * (MI * 16) + lo;
  const int bcol0 = wc * (NJ * 16) + lo;

  // prologue: 3 slots in flight; vmcnt leaves 2 -> slot 0 landed (FIFO-oldest)
  stgA(0); stgB(0); stgA(1); stgB(1); stgA(2); stgB(2);
  VM_MAIN;
  BARRIER();

  f32x4 acc[MI][NJ] = {};
  bf16x8 af[MI / 2], bf[NJ];

  for (int h = 0; h < NS - 3; ++h) { GSLOT(h, true, VM_MAIN); }
  GSLOT(NS - 3, false, VM_ONE);
  GSLOT(NS - 2, false, VM_ZERO);
  GSLOT(NS - 1, false, (void)0);

#pragma unroll
  for (int mi = 0; mi < MI; ++mi) {
    const int row = brow + wr * (MI * 16) + mi * 16 + hi * 4;
#pragma unroll
    for (int nj = 0; nj < NJ; ++nj) {
      const int col = bcol + wc * (NJ * 16) + nj * 16 + lo;
      const float bs = bias[col];
#pragma unroll
      for (int r = 0; r < 4; ++r) {
        float v = acc[mi][nj][r] + bs;
        if constexpr (EPI == 0) {
          if (col < 3072) {
            ((bf16*)out0)[(size_t)(row + r) * 3072 + col] = __float2bfloat16(v);
          } else {
            const float sg = 1.0f / (1.0f + __expf(-v));
            ((bf16*)out1)[(size_t)(row + r) * 2048 + (col - 3072)] =
                __float2bfloat16(v * sg * v);
          }
        } else {
          v += res[(size_t)(row + r) * 2048 + col];
          ((float*)out0)[(size_t)(row + r) * 2048 + col] = v;
        }
      }
    }
  }
}

// --------------------------------------------------------------- attention ----
__global__ __launch_bounds__(256, 4) void attn_fwd(
    const bf16* __restrict__ qkv, const bf16* __restrict__ vtb, bf16* __restrict__ out) {
  __shared__ __align__(16) unsigned char alds[40960];
  unsigned char* Ks = alds;
  unsigned char* Vs = alds + 16384;
  unsigned char* Ps = alds + 32768;
  const int tid = threadIdx.x, lane = tid & 63, w = tid >> 6;
  const int hi = lane >> 4, lo = lane & 15;
  const int qt = blockIdx.x, bh = blockIdx.y;
  const int b = bh >> 4, h = bh & 15, g = h >> 2;
  const size_t tok0 = (size_t)b * 1024;
  const int q0 = qt * 64;

  bf16x8 qf[4];
  {
    const bf16* qp = qkv + (tok0 + q0 + w * 16 + lo) * 3072 + h * 128 + hi * 8;
#pragma unroll
    for (int kc = 0; kc < 4; ++kc) qf[kc] = *(const bf16x8*)(qp + kc * 32);
  }

  float m2 = -1e30f, lsum = 0.f;
  f32x4 oacc[8] = {};
  const float c2 = 0.08838834764831845f * 1.44269504088896f;

  const int o = tid * 16;
  const bf16* kbase = qkv + tok0 * 3072 + 2048 + g * 128;
  const bf16* vbase = vtb + (size_t)(b * 4 + g) * 128 * 1024;
  unsigned char* Pw = Ps + w * 2048;

  for (int t = 0; t < 16; ++t) {
    const int kb = t * 64;
#pragma unroll
    for (int rd = 0; rd < 4; ++rd) {
      const int oo = o + rd * 4096;
      const int rK = oo >> 8, cK = ((oo >> 4) & 15) ^ (rK & 15);
      const int rV = oo >> 7, cV = ((oo >> 4) & 7) ^ (rV & 7);
      async16(Ks + oo, kbase + (size_t)(kb + rK) * 3072 + cK * 8);
      async16(Vs + oo, vbase + (size_t)rV * 1024 + kb + cV * 8);
    }
    __syncthreads();

    f32x4 sc[4] = {};
#pragma unroll
    for (int kc = 0; kc < 4; ++kc) {
#pragma unroll
      for (int kg = 0; kg < 4; ++kg) {
        const int row = kg * 16 + lo;
        bf16x8 kf = *(const bf16x8*)(Ks + row * 256 + ((((kc << 2) + hi) ^ (row & 15)) << 4));
        sc[kg] = MFMA16(kf, qf[kc], sc[kg]);
      }
    }

    float mx = sc[0][0];
#pragma unroll
    for (int kg = 0; kg < 4; ++kg)
#pragma unroll
      for (int r = 0; r < 4; ++r) mx = fmaxf(mx, sc[kg][r]);
    mx = fmaxf(mx, __shfl_xor(mx, 16));
    mx = fmaxf(mx, __shfl_xor(mx, 32));
    mx *= c2;
    const float mn = fmaxf(m2, mx);
    const float corr = fexp2(m2 - mn);
    m2 = mn;

    float rs = 0.f;
#pragma unroll
    for (int kg = 0; kg < 4; ++kg) {
      union { bf16 hh[4]; uint2 v; } pk;
#pragma unroll
      for (int r = 0; r < 4; ++r) {
        const float p = fexp2(sc[kg][r] * c2 - mn);
        rs += p;
        pk.hh[r] = __float2bfloat16(p);
      }
      *(uint2*)(Pw + lo * 128 + ((((kg << 1) + (hi >> 1)) ^ (lo & 7)) << 4) +
                ((hi & 1) << 3)) = pk.v;
    }
    rs += __shfl_xor(rs, 16);
    rs += __shfl_xor(rs, 32);
    lsum = lsum * corr + rs;

    float corr_r[4];
#pragma unroll
    for (int r = 0; r < 4; ++r) corr_r[r] = __shfl(corr, hi * 4 + r);
#pragma unroll
    for (int dg = 0; dg < 8; ++dg)
#pragma unroll
      for (int r = 0; r < 4; ++r) oacc[dg][r] *= corr_r[r];

    asm volatile("s_waitcnt lgkmcnt(0)" ::: "memory");

    bf16x8 pf[2];
#pragma unroll
    for (int kc = 0; kc < 2; ++kc)
      pf[kc] = *(const bf16x8*)(Pw + lo * 128 + ((((kc << 2) + hi) ^ (lo & 7)) << 4));
#pragma unroll
    for (int dg = 0; dg < 8; ++dg) {
#pragma unroll
      for (int kc = 0; kc < 2; ++kc) {
        const int vrow = dg * 16 + lo;
        bf16x8 vf = *(const bf16x8*)(Vs + vrow * 128 + ((((kc << 2) + hi) ^ (vrow & 7)) << 4));
        oacc[dg] = MFMA16(pf[kc], vf, oacc[dg]);
      }
    }
    __syncthreads();
  }

  const float linv = 1.0f / lsum;
  float lr[4];
#pragma unroll
  for (int r = 0; r < 4; ++r) lr[r] = __shfl(linv, hi * 4 + r);
  bf16* op = out + (tok0 + q0 + w * 16 + hi * 4) * 2048 + h * 128 + lo;
#pragma unroll
  for (int dg = 0; dg < 8; ++dg)
#pragma unroll
    for (int r = 0; r < 4; ++r)
      op[(size_t)r * 2048 + dg * 16] = __float2bfloat16(oacc[dg][r] * lr[r]);
}

// ------------------------------------------------------------------ launch ----
extern "C" void kernel_launch(void* const* d_in, const int* in_sizes, int n_in,
                              void* d_out, int out_size, void* d_ws, size_t ws_size,
                              hipStream_t stream) {
  (void)in_sizes; (void)n_in; (void)out_size; (void)ws_size;
  const float* x  = (const float*)d_in[0];
  const float* s1 = (const float*)d_in[1];
  const float* Wq = (const float*)d_in[2];
  const float* bq = (const float*)d_in[3];
  const float* Wk = (const float*)d_in[4];
  const float* bk = (const float*)d_in[5];
  const float* Wv = (const float*)d_in[6];
  const float* bv = (const float*)d_in[7];
  const float* Wo = (const float*)d_in[8];
  const float* bo = (const float*)d_in[9];
  const float* W1 = (const float*)d_in[10];
  const float* b1 = (const float*)d_in[11];
  const float* W2 = (const float*)d_in[12];
  const float* b2 = (const float*)d_in[13];
  float* outp = (float*)d_out;

  char* ws = (char*)d_ws;
  bf16*  xn     = (bf16*)(ws + 0);           // 16.78 MB; dead after gemm8<0>
  bf16*  vtb    = (bf16*)(ws + 0);           // 4.19 MB, aliases dead xn
  bf16*  wcatT  = (bf16*)(ws + 16777216);    // [5120][2048] 20.97 MB; dead after gemm8<0>
  bf16*  attnb  = (bf16*)(ws + 16777216);    // [4096][2048] 16.78 MB, aliases dead wcatT
  float* bcat   = (float*)(ws + 37748736);   // 28 KB
  bf16*  wcat2T = (bf16*)(ws + 37781504);    // [2048][4096] 16.78 MB (Wo|W2 K-concat)
  bf16*  qkvb   = (bf16*)(ws + 54558720);    // [4096][3072] 25.17 MB
  bf16*  gbuf   = (bf16*)(ws + 79724544);    // [4096][2048] 16.78 MB

  const dim3 b32x8(32, 8);
  rmsnorm_cast_k<<<dim3(4096), dim3(256), 0, stream>>>(x, s1, xn);
  concat_bias_k<<<dim3(28), dim3(256), 0, stream>>>(bq, bk, bv, b1, bo, b2, bcat);
  transpose_cast_k<<<dim3(64, 64), b32x8, 0, stream>>>(Wq, wcatT, 2048, 2048, 0, 0);
  transpose_cast_k<<<dim3(16, 64), b32x8, 0, stream>>>(Wk, wcatT, 512, 2048, 2048, 0);
  transpose_cast_k<<<dim3(16, 64), b32x8, 0, stream>>>(Wv, wcatT, 512, 2048, 2560, 0);
  transpose_cast_k<<<dim3(64, 64), b32x8, 0, stream>>>(W1, wcatT, 2048, 2048, 3072, 0);
  transpose_cast_k<<<dim3(64, 64), b32x8, 0, stream>>>(Wo, wcat2T, 2048, 4096, 0, 0);
  transpose_cast_k<<<dim3(64, 64), b32x8, 0, stream>>>(W2, wcat2T, 2048, 4096, 0, 2048);
  // merged QKV + W1: [4096,2048] x [2048,5120], 256x320 tiles -> 256 blocks
  gemm8<8, 5, 2, 4, 0><<<dim3(16, 16), dim3(512), 147456, stream>>>(
      xn, xn, wcatT, bcat, (const float*)nullptr, (void*)qkvb, (void*)gbuf, 2048);
  transpose_v_k<<<dim3(32, 4, 16), b32x8, 0, stream>>>(qkvb, vtb);
  attn_fwd<<<dim3(16, 64), dim3(256), 0, stream>>>(qkvb, vtb, attnb);
  // out = x + attnb@Wo + gbuf@W2 + (bo+b2): [4096,4096]x[4096,2048], 256x128 tiles
  gemm8<4, 4, 4, 2, 1><<<dim3(16, 16), dim3(512), 98304, stream>>>(
      attnb, gbuf, wcat2T, bcat + 5120, x, (void*)outp, (void*)nullptr, 4096);
}

// Round 9
// 240.777 us; speedup vs baseline: 1.2612x; 1.0559x over previous
//
#include <hip/hip_runtime.h>
#include <hip/hip_bf16.h>
#include <cstdint>

using bf16 = __hip_bfloat16;
typedef __attribute__((ext_vector_type(8))) __bf16 bf16x8;
typedef __attribute__((ext_vector_type(4))) float f32x4;

#define MFMA16(a, b, c) __builtin_amdgcn_mfma_f32_16x16x32_bf16((a), (b), (c), 0, 0, 0)

#if __has_builtin(__builtin_amdgcn_exp2f)
__device__ __forceinline__ float fexp2(float x) { return __builtin_amdgcn_exp2f(x); }
#else
__device__ __forceinline__ float fexp2(float x) { return exp2f(x); }
#endif

// Async global->LDS 16B copy. LDS dest must be wave-uniform base + lane*16.
__device__ __forceinline__ void async16(void* lds_ptr, const void* gptr) {
  auto g = reinterpret_cast<__attribute__((address_space(1))) unsigned int*>(
      reinterpret_cast<uintptr_t>(gptr));
  auto l = reinterpret_cast<__attribute__((address_space(3))) unsigned int*>(
      static_cast<unsigned int>(reinterpret_cast<uintptr_t>(lds_ptr)));
  __builtin_amdgcn_global_load_lds(g, l, 16, 0, 0);
}

// ------------------------------------------------------------ fused prep ----
// One launch: rmsnorm-cast (blocks 0..4095), bias concat (4096..4123),
// 6 weight transposes (4124..22555).
// bcat layout: [0..3071]=bq|bk|bv, [3072..5119]=b1, [5120..7167]=bo+b2
__device__ __forceinline__ void tr_body(const float* __restrict__ W,
                                        bf16* __restrict__ Wt, int N, int ldt,
                                        int row_off, int k_off, int lb, int nx,
                                        float (*t)[33], int tx, int ty) {
  const int n0 = (lb % nx) * 32, k0 = (lb / nx) * 32;
#pragma unroll
  for (int i = 0; i < 4; ++i)
    t[ty + 8 * i][tx] = W[(size_t)(k0 + ty + 8 * i) * N + n0 + tx];
  __syncthreads();
#pragma unroll
  for (int i = 0; i < 4; ++i)
    Wt[(size_t)(row_off + n0 + ty + 8 * i) * ldt + k_off + k0 + tx] =
        __float2bfloat16(t[tx][ty + 8 * i]);
}

__global__ __launch_bounds__(256) void prep_k(
    const float* __restrict__ x, const float* __restrict__ s1, bf16* __restrict__ xn,
    const float* __restrict__ Wq, const float* __restrict__ Wk,
    const float* __restrict__ Wv, const float* __restrict__ W1,
    const float* __restrict__ Wo, const float* __restrict__ W2,
    bf16* __restrict__ wcatT, bf16* __restrict__ wcat2T,
    const float* __restrict__ bq, const float* __restrict__ bk,
    const float* __restrict__ bv, const float* __restrict__ b1,
    const float* __restrict__ bo, const float* __restrict__ b2,
    float* __restrict__ bcat) {
  __shared__ float t[32][33];
  const int tid = threadIdx.x;
  int bid = blockIdx.x;
  if (bid < 4096) {
    // RMSNorm row
    const int row = bid;
    const float4* xr = (const float4*)(x + (size_t)row * 2048);
    float4 a = xr[tid * 2], b = xr[tid * 2 + 1];
    float ss = a.x * a.x + a.y * a.y + a.z * a.z + a.w * a.w +
               b.x * b.x + b.y * b.y + b.z * b.z + b.w * b.w;
#pragma unroll
    for (int d = 1; d < 64; d <<= 1) ss += __shfl_xor(ss, d);
    if ((tid & 63) == 0) t[0][tid >> 6] = ss;
    __syncthreads();
    const float rinv =
        rsqrtf((t[0][0] + t[0][1] + t[0][2] + t[0][3]) * (1.0f / 2048.0f) + 1e-6f);
    const float4* sp = (const float4*)s1;
    float4 s0 = sp[tid * 2], s1v = sp[tid * 2 + 1];
    union { bf16 h[8]; bf16x8 v; } o;
    o.h[0] = __float2bfloat16(a.x * rinv * s0.x);
    o.h[1] = __float2bfloat16(a.y * rinv * s0.y);
    o.h[2] = __float2bfloat16(a.z * rinv * s0.z);
    o.h[3] = __float2bfloat16(a.w * rinv * s0.w);
    o.h[4] = __float2bfloat16(b.x * rinv * s1v.x);
    o.h[5] = __float2bfloat16(b.y * rinv * s1v.y);
    o.h[6] = __float2bfloat16(b.z * rinv * s1v.z);
    o.h[7] = __float2bfloat16(b.w * rinv * s1v.w);
    *(bf16x8*)(xn + (size_t)row * 2048 + tid * 8) = o.v;
    return;
  }
  if (bid < 4124) {
    const int i = (bid - 4096) * 256 + tid;
    float v;
    if (i < 2048) v = bq[i];
    else if (i < 2560) v = bk[i - 2048];
    else if (i < 3072) v = bv[i - 2560];
    else if (i < 5120) v = b1[i - 3072];
    else v = bo[i - 5120] + b2[i - 5120];
    bcat[i] = v;
    return;
  }
  bid -= 4124;
  const int tx = tid & 31, ty = tid >> 5;
  if (bid < 4096)       tr_body(Wq, wcatT, 2048, 2048, 0, 0, bid, 64, t, tx, ty);
  else if (bid < 5120)  tr_body(Wk, wcatT, 512, 2048, 2048, 0, bid - 4096, 16, t, tx, ty);
  else if (bid < 6144)  tr_body(Wv, wcatT, 512, 2048, 2560, 0, bid - 5120, 16, t, tx, ty);
  else if (bid < 10240) tr_body(W1, wcatT, 2048, 2048, 3072, 0, bid - 6144, 64, t, tx, ty);
  else if (bid < 14336) tr_body(Wo, wcat2T, 2048, 4096, 0, 0, bid - 10240, 64, t, tx, ty);
  else                  tr_body(W2, wcat2T, 2048, 4096, 0, 2048, bid - 14336, 64, t, tx, ty);
}

// V slice of QKV [4096][3072] (cols 2560..3071) -> Vt bf16 [16][128][1024]
__global__ void transpose_v_k(const bf16* __restrict__ qkv, bf16* __restrict__ vtb) {
  __shared__ bf16 t[32][33];
  const int bh = blockIdx.z, b = bh >> 2, g = bh & 3;
  const int s0 = blockIdx.x * 32, d0 = blockIdx.y * 32;
  const int tx = threadIdx.x, ty = threadIdx.y;
#pragma unroll
  for (int i = 0; i < 4; ++i)
    t[ty + 8 * i][tx] =
        qkv[(size_t)(b * 1024 + s0 + ty + 8 * i) * 3072 + 2560 + g * 128 + d0 + tx];
  __syncthreads();
#pragma unroll
  for (int i = 0; i < 4; ++i)
    vtb[((size_t)bh * 128 + d0 + ty + 8 * i) * 1024 + s0 + tx] = t[tx][ty + 8 * i];
}

// --------------------- 8-wave ring GEMM, fat per-wave panels ----------------
// Same structure as r8; ONLY change: __launch_bounds__(512, 2) caps regs at
// 256/wave (VGPR+AGPR unified) so 2 waves/SIMD are resident -> TLP covers the
// per-phase lgkm0/barrier stalls (r8 ran at 288 regs = 1 wave/SIMD).
#define BARRIER() \
  { asm volatile("" ::: "memory"); __builtin_amdgcn_s_barrier(); asm volatile("" ::: "memory"); }
#define LGKM0() \
  { asm volatile("s_waitcnt lgkmcnt(0)" ::: "memory"); __builtin_amdgcn_sched_barrier(0); }
#define VM_MAIN                                                          \
  { if constexpr (LPS == 4) { asm volatile("s_waitcnt vmcnt(8)" ::: "memory"); } \
    else { asm volatile("s_waitcnt vmcnt(6)" ::: "memory"); }            \
    __builtin_amdgcn_sched_barrier(0); }
#define VM_ONE                                                           \
  { if constexpr (LPS == 4) { asm volatile("s_waitcnt vmcnt(4)" ::: "memory"); } \
    else { asm volatile("s_waitcnt vmcnt(3)" ::: "memory"); }            \
    __builtin_amdgcn_sched_barrier(0); }
#define VM_ZERO \
  { asm volatile("s_waitcnt vmcnt(0)" ::: "memory"); __builtin_amdgcn_sched_barrier(0); }

#define READ_AF(MILO)                                                              \
  { unsigned char* ab_ = lds + (h_ & 3) * SLOTA;                                   \
    _Pragma("unroll") for (int i_ = 0; i_ < MI / 2; ++i_) {                        \
      const int R_ = arow0 + ((MILO) + i_) * 16;                                   \
      af[i_] = *(const bf16x8*)(ab_ + R_ * 64 + ((hi ^ ((R_ >> 1) & 3)) << 4)); } }

#define READ_BF()                                                                  \
  { unsigned char* bb_ = lds + 4 * SLOTA + (h_ & 3) * SLOTB;                       \
    _Pragma("unroll") for (int j_ = 0; j_ < NJ; ++j_) {                            \
      const int S_ = bcol0 + j_ * 16;                                              \
      bf[j_] = *(const bf16x8*)(bb_ + S_ * 64 + ((hi ^ ((S_ >> 1) & 3)) << 4)); } }

#define MFMA_HALF(MILO)                                                            \
  __builtin_amdgcn_s_setprio(1);                                                   \
  _Pragma("unroll") for (int i_ = 0; i_ < MI / 2; ++i_)                            \
    _Pragma("unroll") for (int j_ = 0; j_ < NJ; ++j_)                              \
      acc[(MILO) + i_][j_] = MFMA16(af[i_], bf[j_], acc[(MILO) + i_][j_]);         \
  __builtin_amdgcn_s_setprio(0);

#define GSLOT(H, DOSTG, VMSTMT)                                                    \
  { const int h_ = (H);                                                            \
    READ_AF(0); READ_BF();                                                         \
    if (DOSTG) stgA(h_ + 3);                                                       \
    BARRIER(); LGKM0();                                                            \
    MFMA_HALF(0);                                                                  \
    BARRIER();                                                                     \
    READ_AF(MI / 2);                                                               \
    if (DOSTG) stgB(h_ + 3);                                                       \
    VMSTMT;                                                                        \
    BARRIER(); LGKM0();                                                            \
    MFMA_HALF(MI / 2);                                                             \
    BARRIER(); }

template <int MI, int NJ, int WM, int WN, int EPI>
__global__ __launch_bounds__(512, 2) void gemm8(
    const bf16* __restrict__ A, const bf16* __restrict__ A2,
    const bf16* __restrict__ Bt, const float* __restrict__ bias,
    const float* __restrict__ res, void* __restrict__ out0,
    void* __restrict__ out1, int K) {
  constexpr int BM = WM * MI * 16;
  constexpr int BN = WN * NJ * 16;
  constexpr int SLOTA = BM * 64;   // bytes per A 32-K slot
  constexpr int SLOTB = BN * 64;
  constexpr int NSWA = SLOTA / 8192;
  constexpr int NSWB = SLOTB / 8192;
  constexpr int FRACB = SLOTB % 8192;  // partial sweep (first FRACB/16 threads)
  constexpr int LPS = NSWA + NSWB;     // ledger loads/slot (min over waves)
  extern __shared__ unsigned char lds[];

  const int tid = threadIdx.x, lane = tid & 63, w = tid >> 6;
  const int wr = w / WN, wc = w % WN;
  const int hi = lane >> 4, lo = lane & 15;

  // Rectangular per-XCD mapping over the 16x16 grid (256 blocks):
  // XCD x = lid&7, j = lid>>3; XCD x owns a 4-brow x 8-bcol rectangle.
  const int lid = blockIdx.y * 16 + blockIdx.x;
  const int xj = lid & 7, jj = lid >> 3;
  const int brow = ((xj & 3) * 4 + (jj & 3)) * BM;
  const int bcol = ((xj >> 2) * 8 + (jj >> 2)) * BN;

  const int NS = K >> 5;

  // staging source precompute (A ld fixed 2048; B ld = K)
  size_t offA[NSWA];
#pragma unroll
  for (int i = 0; i < NSWA; ++i) {
    const int o = i * 8192 + tid * 16;
    const int r = o >> 6;
    const int c = ((((o >> 4) & 3) ^ ((r >> 1) & 3)) << 3);
    offA[i] = (size_t)(brow + r) * 2048 + c;
  }
  const bf16* srcB[NSWB + (FRACB ? 1 : 0)];
#pragma unroll
  for (int i = 0; i < NSWB + (FRACB ? 1 : 0); ++i) {
    const int o = i * 8192 + tid * 16;
    const int r = o >> 6;
    const int c = ((((o >> 4) & 3) ^ ((r >> 1) & 3)) << 3);
    srcB[i] = Bt + (size_t)(bcol + r) * K + c;
  }

  auto stgA = [&](int h) {
    unsigned char* ab = lds + (h & 3) * SLOTA;
    const int kb = h * 32;
    const bf16* base;
    int ko;
    if constexpr (EPI == 1) { base = (kb < 2048) ? A : A2; ko = kb & 2047; }
    else { base = A; ko = kb; }
#pragma unroll
    for (int i = 0; i < NSWA; ++i)
      async16(ab + i * 8192 + tid * 16, base + offA[i] + ko);
  };
  auto stgB = [&](int h) {
    unsigned char* bb = lds + 4 * SLOTA + (h & 3) * SLOTB;
    const int kb = h * 32;
#pragma unroll
    for (int i = 0; i < NSWB; ++i)
      async16(bb + i * 8192 + tid * 16, srcB[i] + kb);
    if constexpr (FRACB != 0) {
      if (tid < FRACB / 16)
        async16(bb + NSWB * 8192 + tid * 16, srcB[NSWB] + kb);
    }
  };

  const int arow0 = wr * (MI * 16) + lo;
  const int bcol0 = wc * (NJ * 16) + lo;

  // prologue: 3 slots in flight; vmcnt leaves 2 -> slot 0 landed (FIFO-oldest)
  stgA(0); stgB(0); stgA(1); stgB(1); stgA(2); stgB(2);
  VM_MAIN;
  BARRIER();

  f32x4 acc[MI][NJ] = {};
  bf16x8 af[MI / 2], bf[NJ];

  for (int h = 0; h < NS - 3; ++h) { GSLOT(h, true, VM_MAIN); }
  GSLOT(NS - 3, false, VM_ONE);
  GSLOT(NS - 2, false, VM_ZERO);
  GSLOT(NS - 1, false, (void)0);

#pragma unroll
  for (int mi = 0; mi < MI; ++mi) {
    const int row = brow + wr * (MI * 16) + mi * 16 + hi * 4;
#pragma unroll
    for (int nj = 0; nj < NJ; ++nj) {
      const int col = bcol + wc * (NJ * 16) + nj * 16 + lo;
      const float bs = bias[col];
#pragma unroll
      for (int r = 0; r < 4; ++r) {
        float v = acc[mi][nj][r] + bs;
        if constexpr (EPI == 0) {
          if (col < 3072) {
            ((bf16*)out0)[(size_t)(row + r) * 3072 + col] = __float2bfloat16(v);
          } else {
            const float sg = 1.0f / (1.0f + __expf(-v));
            ((bf16*)out1)[(size_t)(row + r) * 2048 + (col - 3072)] =
                __float2bfloat16(v * sg * v);
          }
        } else {
          v += res[(size_t)(row + r) * 2048 + col];
          ((float*)out0)[(size_t)(row + r) * 2048 + col] = v;
        }
      }
    }
  }
}

// --------------------------------------------------------------- attention ----
__global__ __launch_bounds__(256, 4) void attn_fwd(
    const bf16* __restrict__ qkv, const bf16* __restrict__ vtb, bf16* __restrict__ out) {
  __shared__ __align__(16) unsigned char alds[40960];
  unsigned char* Ks = alds;
  unsigned char* Vs = alds + 16384;
  unsigned char* Ps = alds + 32768;
  const int tid = threadIdx.x, lane = tid & 63, w = tid >> 6;
  const int hi = lane >> 4, lo = lane & 15;
  const int qt = blockIdx.x, bh = blockIdx.y;
  const int b = bh >> 4, h = bh & 15, g = h >> 2;
  const size_t tok0 = (size_t)b * 1024;
  const int q0 = qt * 64;

  bf16x8 qf[4];
  {
    const bf16* qp = qkv + (tok0 + q0 + w * 16 + lo) * 3072 + h * 128 + hi * 8;
#pragma unroll
    for (int kc = 0; kc < 4; ++kc) qf[kc] = *(const bf16x8*)(qp + kc * 32);
  }

  float m2 = -1e30f, lsum = 0.f;
  f32x4 oacc[8] = {};
  const float c2 = 0.08838834764831845f * 1.44269504088896f;

  const int o = tid * 16;
  const bf16* kbase = qkv + tok0 * 3072 + 2048 + g * 128;
  const bf16* vbase = vtb + (size_t)(b * 4 + g) * 128 * 1024;
  unsigned char* Pw = Ps + w * 2048;

  for (int t = 0; t < 16; ++t) {
    const int kb = t * 64;
#pragma unroll
    for (int rd = 0; rd < 4; ++rd) {
      const int oo = o + rd * 4096;
      const int rK = oo >> 8, cK = ((oo >> 4) & 15) ^ (rK & 15);
      const int rV = oo >> 7, cV = ((oo >> 4) & 7) ^ (rV & 7);
      async16(Ks + oo, kbase + (size_t)(kb + rK) * 3072 + cK * 8);
      async16(Vs + oo, vbase + (size_t)rV * 1024 + kb + cV * 8);
    }
    __syncthreads();

    f32x4 sc[4] = {};
    __builtin_amdgcn_s_setprio(1);
#pragma unroll
    for (int kc = 0; kc < 4; ++kc) {
#pragma unroll
      for (int kg = 0; kg < 4; ++kg) {
        const int row = kg * 16 + lo;
        bf16x8 kf = *(const bf16x8*)(Ks + row * 256 + ((((kc << 2) + hi) ^ (row & 15)) << 4));
        sc[kg] = MFMA16(kf, qf[kc], sc[kg]);
      }
    }
    __builtin_amdgcn_s_setprio(0);

    float mx = sc[0][0];
#pragma unroll
    for (int kg = 0; kg < 4; ++kg)
#pragma unroll
      for (int r = 0; r < 4; ++r) mx = fmaxf(mx, sc[kg][r]);
    mx = fmaxf(mx, __shfl_xor(mx, 16));
    mx = fmaxf(mx, __shfl_xor(mx, 32));
    mx *= c2;
    const float mn = fmaxf(m2, mx);
    const float corr = fexp2(m2 - mn);
    m2 = mn;

    float rs = 0.f;
#pragma unroll
    for (int kg = 0; kg < 4; ++kg) {
      union { bf16 hh[4]; uint2 v; } pk;
#pragma unroll
      for (int r = 0; r < 4; ++r) {
        const float p = fexp2(sc[kg][r] * c2 - mn);
        rs += p;
        pk.hh[r] = __float2bfloat16(p);
      }
      *(uint2*)(Pw + lo * 128 + ((((kg << 1) + (hi >> 1)) ^ (lo & 7)) << 4) +
                ((hi & 1) << 3)) = pk.v;
    }
    rs += __shfl_xor(rs, 16);
    rs += __shfl_xor(rs, 32);
    lsum = lsum * corr + rs;

    float corr_r[4];
#pragma unroll
    for (int r = 0; r < 4; ++r) corr_r[r] = __shfl(corr, hi * 4 + r);
#pragma unroll
    for (int dg = 0; dg < 8; ++dg)
#pragma unroll
      for (int r = 0; r < 4; ++r) oacc[dg][r] *= corr_r[r];

    asm volatile("s_waitcnt lgkmcnt(0)" ::: "memory");

    bf16x8 pf[2];
#pragma unroll
    for (int kc = 0; kc < 2; ++kc)
      pf[kc] = *(const bf16x8*)(Pw + lo * 128 + ((((kc << 2) + hi) ^ (lo & 7)) << 4));
    __builtin_amdgcn_s_setprio(1);
#pragma unroll
    for (int dg = 0; dg < 8; ++dg) {
#pragma unroll
      for (int kc = 0; kc < 2; ++kc) {
        const int vrow = dg * 16 + lo;
        bf16x8 vf = *(const bf16x8*)(Vs + vrow * 128 + ((((kc << 2) + hi) ^ (vrow & 7)) << 4));
        oacc[dg] = MFMA16(pf[kc], vf, oacc[dg]);
      }
    }
    __builtin_amdgcn_s_setprio(0);
    __syncthreads();
  }

  const float linv = 1.0f / lsum;
  float lr[4];
#pragma unroll
  for (int r = 0; r < 4; ++r) lr[r] = __shfl(linv, hi * 4 + r);
  bf16* op = out + (tok0 + q0 + w * 16 + hi * 4) * 2048 + h * 128 + lo;
#pragma unroll
  for (int dg = 0; dg < 8; ++dg)
#pragma unroll
    for (int r = 0; r < 4; ++r)
      op[(size_t)r * 2048 + dg * 16] = __float2bfloat16(oacc[dg][r] * lr[r]);
}

// ------------------------------------------------------------------ launch ----
extern "C" void kernel_launch(void* const* d_in, const int* in_sizes, int n_in,
                              void* d_out, int out_size, void* d_ws, size_t ws_size,
                              hipStream_t stream) {
  (void)in_sizes; (void)n_in; (void)out_size; (void)ws_size;
  const float* x  = (const float*)d_in[0];
  const float* s1 = (const float*)d_in[1];
  const float* Wq = (const float*)d_in[2];
  const float* bq = (const float*)d_in[3];
  const float* Wk = (const float*)d_in[4];
  const float* bk = (const float*)d_in[5];
  const float* Wv = (const float*)d_in[6];
  const float* bv = (const float*)d_in[7];
  const float* Wo = (const float*)d_in[8];
  const float* bo = (const float*)d_in[9];
  const float* W1 = (const float*)d_in[10];
  const float* b1 = (const float*)d_in[11];
  const float* W2 = (const float*)d_in[12];
  const float* b2 = (const float*)d_in[13];
  float* outp = (float*)d_out;

  char* ws = (char*)d_ws;
  bf16*  xn     = (bf16*)(ws + 0);           // 16.78 MB; dead after gemm8<0>
  bf16*  vtb    = (bf16*)(ws + 0);           // 4.19 MB, aliases dead xn
  bf16*  wcatT  = (bf16*)(ws + 16777216);    // [5120][2048] 20.97 MB; dead after gemm8<0>
  bf16*  attnb  = (bf16*)(ws + 16777216);    // [4096][2048] 16.78 MB, aliases dead wcatT
  float* bcat   = (float*)(ws + 37748736);   // 28 KB
  bf16*  wcat2T = (bf16*)(ws + 37781504);    // [2048][4096] 16.78 MB (Wo|W2 K-concat)
  bf16*  qkvb   = (bf16*)(ws + 54558720);    // [4096][3072] 25.17 MB
  bf16*  gbuf   = (bf16*)(ws + 79724544);    // [4096][2048] 16.78 MB

  // fused prep: rmsnorm + bias concat + all weight transposes
  prep_k<<<dim3(22556), dim3(256), 0, stream>>>(
      x, s1, xn, Wq, Wk, Wv, W1, Wo, W2, wcatT, wcat2T,
      bq, bk, bv, b1, bo, b2, bcat);
  // merged QKV + W1: [4096,2048] x [2048,5120], 256x320 tiles -> 256 blocks
  gemm8<8, 5, 2, 4, 0><<<dim3(16, 16), dim3(512), 147456, stream>>>(
      xn, xn, wcatT, bcat, (const float*)nullptr, (void*)qkvb, (void*)gbuf, 2048);
  transpose_v_k<<<dim3(32, 4, 16), dim3(32, 8), 0, stream>>>(qkvb, vtb);
  attn_fwd<<<dim3(16, 64), dim3(256), 0, stream>>>(qkvb, vtb, attnb);
  // out = x + attnb@Wo + gbuf@W2 + (bo+b2): [4096,4096]x[4096,2048], 256x128 tiles
  gemm8<4, 4, 4, 2, 1><<<dim3(16, 16), dim3(512), 98304, stream>>>(
      attnb, gbuf, wcat2T, bcat + 5120, x, (void*)outp, (void*)nullptr, 4096);
}